// Round 7
// baseline (615.237 us; speedup 1.0000x reference)
//
#include <hip/hip_runtime.h>
#include <hip/hip_bf16.h>

#define NS 8
#define NF 210
#define HID 128

typedef __attribute__((ext_vector_type(8))) short short8v;     // 8 bf16 = 4 VGPR MFMA A/B frag
typedef __attribute__((ext_vector_type(4))) float float4v;     // MFMA C/D frag
typedef float float4a __attribute__((ext_vector_type(4)));                 // 16B-aligned load
typedef float float4u __attribute__((ext_vector_type(4), aligned(4)));     // 4B-aligned global read
typedef float float2u __attribute__((ext_vector_type(2), aligned(8)));

__device__ __forceinline__ short f2b(float f) {
    __hip_bfloat16 h = __float2bfloat16(f);   // RNE; pairs fuse to v_cvt_pk_bf16_f32
    return __builtin_bit_cast(short, h);
}

#define MFMA16(a, b, cacc) __builtin_amdgcn_mfma_f32_16x16x32_bf16(a, b, cacc, 0, 0, 0)

// ---------------------------------------------------------------------------
// pre_kernel: blocks [0,304) = weight repack; blocks [304,816) = station path.
// Weight repack (W^T A-frags, lane-linear per (nc,kc) -> conflict-free
// ds_read_b128):
//   W1 : [0,28672)         idx = (((nc*7+kc)*4+kg)*16 + c)*8 + j
//   WsL: 28672+l*16384 +   idx = (((nc*4+kc)*4+kg)*16 + c)*8 + j
//   frag elem j of lane (c,kg): n = 16nc+c, k = kc*32+16(j>>2)+4kg+(j&3)
// Station path emits c_all[g][l][:] = mean_l[g] @ Wneigh_hf[l] + b_hf[l] and
// d_out[g] = rs[g]*W_out[0] + b_out (feature kernel atomic-adds rf part).
// ---------------------------------------------------------------------------
__global__ __launch_bounds__(256) void pre_kernel(
    const float* __restrict__ W1_ft, const float* __restrict__ Wself_hf,
    unsigned short* __restrict__ wsb,
    const float* __restrict__ h_st, const float* __restrict__ W1_st, const float* __restrict__ b1_st,
    const float* __restrict__ Wself_tt, const float* __restrict__ Wneigh_tt, const float* __restrict__ b_tt,
    const float* __restrict__ Wneigh_hf, const float* __restrict__ b_hf,
    const float* __restrict__ W2_st, const float* __restrict__ b2_st,
    const float* __restrict__ W_out, const float* __restrict__ b_out,
    float* __restrict__ c_all, float* __restrict__ d_out) {
    __shared__ float hs[16][HID];
    __shared__ float hstile[16][NS];
    __shared__ float m[2][HID];
    __shared__ float ctt[2][HID];
    __shared__ float gsum[2];
    int tid = threadIdx.x;

    if (blockIdx.x < 304) {
        int t = blockIdx.x * 256 + tid;
        if (t < 28672) {
            int j = t & 7, cc = (t >> 3) & 15, kg = (t >> 7) & 3, q = t >> 9;
            int kc = q % 7, nc = q / 7;
            int n = nc * 16 + cc;
            int k = kc * 32 + ((j >> 2) << 4) + (kg << 2) + (j & 3);
            wsb[t] = (unsigned short)f2b(k < NF ? W1_ft[k * HID + n] : 0.f);
        } else {
            int u = t - 28672, l = u >> 14, v = u & 16383;
            int j = v & 7, cc = (v >> 3) & 15, kg = (v >> 7) & 3, kc = (v >> 9) & 3, nc = v >> 11;
            int n = nc * 16 + cc;
            int k = kc * 32 + ((j >> 2) << 4) + (kg << 2) + (j & 3);
            wsb[t] = (unsigned short)f2b(Wself_hf[(l * HID + k) * HID + n]);
        }
        return;
    }

    int bid = blockIdx.x - 304;
    int j = tid & 127, h = tid >> 7;
    int gblk = bid * 2;

    if (tid < 2) gsum[tid] = 0.f;
    if (tid < 128) hstile[tid >> 3][tid & 7] = h_st[bid * 128 + tid];
    __syncthreads();

    {
        float w1r[8];
#pragma unroll
        for (int k = 0; k < 8; k++) w1r[k] = W1_st[k * HID + j];
        float b1 = b1_st[j];
#pragma unroll
        for (int si = 0; si < 8; si++) {
            int s = 2 * si + h;
            float acc = b1;
#pragma unroll
            for (int k = 0; k < 8; k++) acc += hstile[s][k] * w1r[k];
            hs[s][j] = acc;
        }
    }
    __syncthreads();

    for (int l = 0; l < 3; l++) {
        {
            float s0 = 0.f;
#pragma unroll
            for (int s = 0; s < 8; s++) s0 += hs[h * 8 + s][j];
            m[h][j] = s0 * 0.125f;
        }
        __syncthreads();
        {
            float att = b_tt[l * HID + j], ahf = b_hf[l * HID + j];
            const float* wtt = Wneigh_tt + l * HID * HID + j;
            const float* whf = Wneigh_hf + l * HID * HID + j;
            const float* mg = m[h];
#pragma unroll 4
            for (int k = 0; k < HID; k++) {
                float mv = mg[k];
                att += mv * wtt[k * HID];
                ahf += mv * whf[k * HID];
            }
            ctt[h][j] = att;
            c_all[((gblk + h) * 3 + l) * HID + j] = ahf;
        }
        __syncthreads();
        float tmp[8];
#pragma unroll
        for (int si = 0; si < 8; si++) tmp[si] = ctt[(2 * si + h) >> 3][j];
        const float* wsp = Wself_tt + l * HID * HID + j;
        for (int k4 = 0; k4 < HID / 4; k4++) {
            float w0 = wsp[(4 * k4 + 0) * HID];
            float wa = wsp[(4 * k4 + 1) * HID];
            float wb = wsp[(4 * k4 + 2) * HID];
            float wc = wsp[(4 * k4 + 3) * HID];
#pragma unroll
            for (int si = 0; si < 8; si++) {
                float4a hv = *(const float4a*)&hs[2 * si + h][4 * k4];
                tmp[si] += hv.x * w0 + hv.y * wa + hv.z * wb + hv.w * wc;
            }
        }
        __syncthreads();
#pragma unroll
        for (int si = 0; si < 8; si++) hs[2 * si + h][j] = fmaxf(tmp[si], 0.f);
        __syncthreads();
    }

    int w = tid >> 6, lane = tid & 63;
    float w2a = W2_st[lane], w2b = W2_st[lane + 64];
    float p = 0.f;
#pragma unroll
    for (int r = 0; r < 4; r++) {
        int row = w * 4 + r;
        p += hs[row][lane] * w2a + hs[row][lane + 64] * w2b;
    }
#pragma unroll
    for (int off = 32; off; off >>= 1) p += __shfl_xor(p, off);
    if (lane == 0) atomicAdd(&gsum[w >> 1], p);
    __syncthreads();
    if (tid < 2) {
        float rs = gsum[tid] + 8.f * b2_st[0];
        d_out[gblk + tid] = rs * W_out[0] + b_out[0];
    }
}

// ---------------------------------------------------------------------------
// Feature path v6: 256 persistent blocks x 1024 thr (16 waves, 1 block/CU due
// to 155,648 B LDS -> 4 waves/SIMD, VGPR cap 128 via launch_bounds(1024,1)
// [2nd arg = min BLOCKS/CU empirically: (512,2)->128, (1024,4)->64].
// Full weight set staged once; waves free-run over 32-row units.
// Layer-0 is kc-OUTER: per kc load 4x16B h_ft, convert, 16 MFMAs — live set
// ~95 VGPR (v5 held 104 fp32 staging regs -> spilled at cap).
// ---------------------------------------------------------------------------
__global__ __launch_bounds__(1024, 1) void feature_kernel(
    const float* __restrict__ h_ft, const float* __restrict__ b1_ft,
    const float* __restrict__ W2_ft, const float* __restrict__ b2_ft,
    const float* __restrict__ W_out,
    const unsigned short* __restrict__ wfrag, const float* __restrict__ c_all,
    float* __restrict__ d_out) {
    __shared__ __align__(16) unsigned short lw[77824];   // 155,648 B
    int tid = threadIdx.x;
    {
        const int4* gs = (const int4*)wfrag;
        int4* ls = (int4*)lw;
#pragma unroll
        for (int i = 0; i < 10; i++) {
            int idx = i * 1024 + tid;
            if (idx < 9728) ls[idx] = gs[idx];
        }
    }
    __syncthreads();   // only barrier

    const int w = tid >> 6, lane = tid & 63;
    const int c = lane & 15, kg = lane >> 4;
    const int wid = blockIdx.x * 16 + w;
    const short8v* w1l = (const short8v*)lw + lane;

    for (int u = wid; u < 6720; u += 4096) {
        const int rb = u * 32;
        const int row0 = rb + c, row1 = rb + 16 + c;
        const int gA = row0 / NF, gB = row1 / NF;
        const float* a0 = h_ft + (size_t)row0 * NF;
        const float* a1 = h_ft + (size_t)row1 * NF;

        float4v acc0[8], acc1[8];
#pragma unroll
        for (int nc = 0; nc < 8; nc++)
#pragma unroll
            for (int r = 0; r < 4; r++) { acc0[nc][r] = 0.f; acc1[nc][r] = 0.f; }

        // ---- layer 0: kc-outer, load->convert->16 MFMA per kc (low live set) ----
#pragma unroll
        for (int kc = 0; kc < 7; kc++) {
            const int k0 = kc * 32 + 4 * kg;
            float4u va0 = *(const float4u*)&a0[k0];
            float4u va1 = *(const float4u*)&a1[k0];
            float4u vb0, vb1;
            if (kc < 6) {
                vb0 = *(const float4u*)&a0[k0 + 16];
                vb1 = *(const float4u*)&a1[k0 + 16];
            } else if (kg == 0) {
                float2u t0 = *(const float2u*)&a0[208];
                float2u t1 = *(const float2u*)&a1[208];
                vb0[0] = t0[0]; vb0[1] = t0[1]; vb0[2] = 0.f; vb0[3] = 0.f;
                vb1[0] = t1[0]; vb1[1] = t1[1]; vb1[2] = 0.f; vb1[3] = 0.f;
            } else {
                vb0[0] = vb0[1] = vb0[2] = vb0[3] = 0.f;
                vb1[0] = vb1[1] = vb1[2] = vb1[3] = 0.f;
            }
            short8v bx0, bx1;
#pragma unroll
            for (int r = 0; r < 4; r++) {
                bx0[r]     = f2b(va0[r]);
                bx0[4 + r] = f2b(vb0[r]);
                bx1[r]     = f2b(va1[r]);
                bx1[4 + r] = f2b(vb1[r]);
            }
            __builtin_amdgcn_s_setprio(1);
#pragma unroll
            for (int nc = 0; nc < 8; nc++) {
                short8v wv = w1l[(nc * 7 + kc) * 64];
                acc0[nc] = MFMA16(wv, bx0, acc0[nc]);
                acc1[nc] = MFMA16(wv, bx1, acc1[nc]);
            }
            __builtin_amdgcn_s_setprio(0);
        }

        // ---- transition: +b1, pack next-layer B-frags (acc dies into bf) ----
        short8v bf0[4], bf1[4];
#pragma unroll
        for (int k2 = 0; k2 < 4; k2++) {
            float4a bA = *(const float4a*)&b1_ft[k2 * 32 + 4 * kg];
            float4a bB = *(const float4a*)&b1_ft[k2 * 32 + 16 + 4 * kg];
#pragma unroll
            for (int r = 0; r < 4; r++) {
                bf0[k2][r]     = f2b(acc0[2 * k2][r]     + bA[r]);
                bf0[k2][4 + r] = f2b(acc0[2 * k2 + 1][r] + bB[r]);
                bf1[k2][r]     = f2b(acc1[2 * k2][r]     + bA[r]);
                bf1[k2][4 + r] = f2b(acc1[2 * k2 + 1][r] + bB[r]);
            }
        }

        // ---- conv layers 0,1 ----
#pragma unroll
        for (int l = 0; l < 2; l++) {
            const short8v* wsl = (const short8v*)(lw + 28672 + l * 16384) + lane;
#pragma unroll
            for (int nc = 0; nc < 8; nc++)
#pragma unroll
                for (int r = 0; r < 4; r++) { acc0[nc][r] = 0.f; acc1[nc][r] = 0.f; }
            __builtin_amdgcn_s_setprio(1);
#pragma unroll
            for (int kc = 0; kc < 4; kc++)
#pragma unroll
                for (int nc = 0; nc < 8; nc++) {
                    short8v wv = wsl[(nc * 4 + kc) * 64];
                    acc0[nc] = MFMA16(wv, bf0[kc], acc0[nc]);
                    acc1[nc] = MFMA16(wv, bf1[kc], acc1[nc]);
                }
            __builtin_amdgcn_s_setprio(0);
            const float* cp0 = c_all + (gA * 3 + l) * HID;
            const float* cp1 = c_all + (gB * 3 + l) * HID;
#pragma unroll
            for (int k2 = 0; k2 < 4; k2++) {
                float4a cA0 = *(const float4a*)&cp0[k2 * 32 + 4 * kg];
                float4a cB0 = *(const float4a*)&cp0[k2 * 32 + 16 + 4 * kg];
                float4a cA1 = *(const float4a*)&cp1[k2 * 32 + 4 * kg];
                float4a cB1 = *(const float4a*)&cp1[k2 * 32 + 16 + 4 * kg];
#pragma unroll
                for (int r = 0; r < 4; r++) {
                    bf0[k2][r]     = f2b(fmaxf(acc0[2 * k2][r]     + cA0[r], 0.f));
                    bf0[k2][4 + r] = f2b(fmaxf(acc0[2 * k2 + 1][r] + cB0[r], 0.f));
                    bf1[k2][r]     = f2b(fmaxf(acc1[2 * k2][r]     + cA1[r], 0.f));
                    bf1[k2][4 + r] = f2b(fmaxf(acc1[2 * k2 + 1][r] + cB1[r], 0.f));
                }
            }
        }

        // ---- conv layer 2 + fused epilogue ----
        {
            const short8v* ws2 = (const short8v*)(lw + 61440) + lane;
#pragma unroll
            for (int nc = 0; nc < 8; nc++)
#pragma unroll
                for (int r = 0; r < 4; r++) { acc0[nc][r] = 0.f; acc1[nc][r] = 0.f; }
            __builtin_amdgcn_s_setprio(1);
#pragma unroll
            for (int kc = 0; kc < 4; kc++)
#pragma unroll
                for (int nc = 0; nc < 8; nc++) {
                    short8v wv = ws2[(nc * 4 + kc) * 64];
                    acc0[nc] = MFMA16(wv, bf0[kc], acc0[nc]);
                    acc1[nc] = MFMA16(wv, bf1[kc], acc1[nc]);
                }
            __builtin_amdgcn_s_setprio(0);
            const float* cp0 = c_all + (gA * 3 + 2) * HID;
            const float* cp1 = c_all + (gB * 3 + 2) * HID;
            float p0 = 0.f, p1 = 0.f;
#pragma unroll
            for (int nc = 0; nc < 8; nc++) {
                float4a w2v = *(const float4a*)&W2_ft[nc * 16 + 4 * kg];
                float4a cv0 = *(const float4a*)&cp0[nc * 16 + 4 * kg];
                float4a cv1 = *(const float4a*)&cp1[nc * 16 + 4 * kg];
#pragma unroll
                for (int r = 0; r < 4; r++) {
                    p0 += fmaxf(acc0[nc][r] + cv0[r], 0.f) * w2v[r];
                    p1 += fmaxf(acc1[nc][r] + cv1[r], 0.f) * w2v[r];
                }
            }
            p0 += __shfl_xor(p0, 16); p0 += __shfl_xor(p0, 32);
            p1 += __shfl_xor(p1, 16); p1 += __shfl_xor(p1, 32);
            if (kg == 0) {
                float wo1 = W_out[1], b2v = b2_ft[0];
                atomicAdd(&d_out[gA], (p0 + b2v) * wo1);
                atomicAdd(&d_out[gB], (p1 + b2v) * wo1);
            }
        }
    }
}

extern "C" void kernel_launch(void* const* d_in, const int* in_sizes, int n_in,
                              void* d_out, int out_size, void* d_ws, size_t ws_size,
                              hipStream_t stream) {
    const float* h_st     = (const float*)d_in[0];
    const float* h_ft     = (const float*)d_in[1];
    const float* Wself_tt = (const float*)d_in[2];
    const float* Wneigh_tt= (const float*)d_in[3];
    const float* b_tt     = (const float*)d_in[4];
    const float* Wself_hf = (const float*)d_in[5];
    const float* Wneigh_hf= (const float*)d_in[6];
    const float* b_hf     = (const float*)d_in[7];
    const float* W1_st    = (const float*)d_in[8];
    const float* b1_st    = (const float*)d_in[9];
    const float* W1_ft    = (const float*)d_in[10];
    const float* b1_ft    = (const float*)d_in[11];
    const float* W2_st    = (const float*)d_in[12];
    const float* b2_st    = (const float*)d_in[13];
    const float* W2_ft    = (const float*)d_in[14];
    const float* b2_ft    = (const float*)d_in[15];
    const float* W_out    = (const float*)d_in[16];
    const float* b_out    = (const float*)d_in[17];
    // dense edge lists d_in[18..21] never read

    unsigned short* wfrag = (unsigned short*)d_ws;
    float* c_all = (float*)((char*)d_ws + 155648);

    pre_kernel<<<dim3(816), dim3(256), 0, stream>>>(
        W1_ft, Wself_hf, wfrag,
        h_st, W1_st, b1_st, Wself_tt, Wneigh_tt, b_tt, Wneigh_hf, b_hf,
        W2_st, b2_st, W_out, b_out, c_all, (float*)d_out);
    feature_kernel<<<dim3(256), dim3(1024), 0, stream>>>(
        h_ft, b1_ft, W2_ft, b2_ft, W_out, wfrag, c_all, (float*)d_out);
}

// Round 8
// 598.962 us; speedup vs baseline: 1.0272x; 1.0272x over previous
//
#include <hip/hip_runtime.h>
#include <hip/hip_bf16.h>

#define NS 8
#define NF 210
#define HID 128

typedef __attribute__((ext_vector_type(8))) short short8v;     // 8 bf16 = 4 VGPR MFMA A/B frag
typedef __attribute__((ext_vector_type(4))) float float4v;     // MFMA C/D frag
typedef float float4a __attribute__((ext_vector_type(4)));                 // 16B-aligned load
typedef float float4u __attribute__((ext_vector_type(4), aligned(4)));     // 4B-aligned global read
typedef float float2u __attribute__((ext_vector_type(2), aligned(8)));

__device__ __forceinline__ short f2b(float f) {
    __hip_bfloat16 h = __float2bfloat16(f);   // RNE; pairs fuse to v_cvt_pk_bf16_f32
    return __builtin_bit_cast(short, h);
}

#define MFMA16(a, b, cacc) __builtin_amdgcn_mfma_f32_16x16x32_bf16(a, b, cacc, 0, 0, 0)

// ---------------------------------------------------------------------------
// pre_kernel: blocks [0,304) = weight repack; blocks [304,816) = station path.
// Weight repack (W^T A-frags, lane-linear per (nc,kc) -> conflict-free
// ds_read_b128):
//   W1 : [0,28672)         idx = (((nc*7+kc)*4+kg)*16 + c)*8 + j
//   WsL: 28672+l*16384 +   idx = (((nc*4+kc)*4+kg)*16 + c)*8 + j
//   frag elem j of lane (c,kg): n = 16nc+c, k = kc*32+16(j>>2)+4kg+(j&3)
// Station path emits c_all[g][l][:] = mean_l[g] @ Wneigh_hf[l] + b_hf[l] and
// d_out[g] = rs[g]*W_out[0] + b_out (feature kernel atomic-adds rf part).
// ---------------------------------------------------------------------------
__global__ __launch_bounds__(256) void pre_kernel(
    const float* __restrict__ W1_ft, const float* __restrict__ Wself_hf,
    unsigned short* __restrict__ wsb,
    const float* __restrict__ h_st, const float* __restrict__ W1_st, const float* __restrict__ b1_st,
    const float* __restrict__ Wself_tt, const float* __restrict__ Wneigh_tt, const float* __restrict__ b_tt,
    const float* __restrict__ Wneigh_hf, const float* __restrict__ b_hf,
    const float* __restrict__ W2_st, const float* __restrict__ b2_st,
    const float* __restrict__ W_out, const float* __restrict__ b_out,
    float* __restrict__ c_all, float* __restrict__ d_out) {
    __shared__ float hs[16][HID];
    __shared__ float hstile[16][NS];
    __shared__ float m[2][HID];
    __shared__ float ctt[2][HID];
    __shared__ float gsum[2];
    int tid = threadIdx.x;

    if (blockIdx.x < 304) {
        int t = blockIdx.x * 256 + tid;
        if (t < 28672) {
            int j = t & 7, cc = (t >> 3) & 15, kg = (t >> 7) & 3, q = t >> 9;
            int kc = q % 7, nc = q / 7;
            int n = nc * 16 + cc;
            int k = kc * 32 + ((j >> 2) << 4) + (kg << 2) + (j & 3);
            wsb[t] = (unsigned short)f2b(k < NF ? W1_ft[k * HID + n] : 0.f);
        } else {
            int u = t - 28672, l = u >> 14, v = u & 16383;
            int j = v & 7, cc = (v >> 3) & 15, kg = (v >> 7) & 3, kc = (v >> 9) & 3, nc = v >> 11;
            int n = nc * 16 + cc;
            int k = kc * 32 + ((j >> 2) << 4) + (kg << 2) + (j & 3);
            wsb[t] = (unsigned short)f2b(Wself_hf[(l * HID + k) * HID + n]);
        }
        return;
    }

    int bid = blockIdx.x - 304;
    int j = tid & 127, h = tid >> 7;
    int gblk = bid * 2;

    if (tid < 2) gsum[tid] = 0.f;
    if (tid < 128) hstile[tid >> 3][tid & 7] = h_st[bid * 128 + tid];
    __syncthreads();

    {
        float w1r[8];
#pragma unroll
        for (int k = 0; k < 8; k++) w1r[k] = W1_st[k * HID + j];
        float b1 = b1_st[j];
#pragma unroll
        for (int si = 0; si < 8; si++) {
            int s = 2 * si + h;
            float acc = b1;
#pragma unroll
            for (int k = 0; k < 8; k++) acc += hstile[s][k] * w1r[k];
            hs[s][j] = acc;
        }
    }
    __syncthreads();

    for (int l = 0; l < 3; l++) {
        {
            float s0 = 0.f;
#pragma unroll
            for (int s = 0; s < 8; s++) s0 += hs[h * 8 + s][j];
            m[h][j] = s0 * 0.125f;
        }
        __syncthreads();
        {
            float att = b_tt[l * HID + j], ahf = b_hf[l * HID + j];
            const float* wtt = Wneigh_tt + l * HID * HID + j;
            const float* whf = Wneigh_hf + l * HID * HID + j;
            const float* mg = m[h];
#pragma unroll 4
            for (int k = 0; k < HID; k++) {
                float mv = mg[k];
                att += mv * wtt[k * HID];
                ahf += mv * whf[k * HID];
            }
            ctt[h][j] = att;
            c_all[((gblk + h) * 3 + l) * HID + j] = ahf;
        }
        __syncthreads();
        float tmp[8];
#pragma unroll
        for (int si = 0; si < 8; si++) tmp[si] = ctt[(2 * si + h) >> 3][j];
        const float* wsp = Wself_tt + l * HID * HID + j;
        for (int k4 = 0; k4 < HID / 4; k4++) {
            float w0 = wsp[(4 * k4 + 0) * HID];
            float wa = wsp[(4 * k4 + 1) * HID];
            float wb = wsp[(4 * k4 + 2) * HID];
            float wc = wsp[(4 * k4 + 3) * HID];
#pragma unroll
            for (int si = 0; si < 8; si++) {
                float4a hv = *(const float4a*)&hs[2 * si + h][4 * k4];
                tmp[si] += hv.x * w0 + hv.y * wa + hv.z * wb + hv.w * wc;
            }
        }
        __syncthreads();
#pragma unroll
        for (int si = 0; si < 8; si++) hs[2 * si + h][j] = fmaxf(tmp[si], 0.f);
        __syncthreads();
    }

    int w = tid >> 6, lane = tid & 63;
    float w2a = W2_st[lane], w2b = W2_st[lane + 64];
    float p = 0.f;
#pragma unroll
    for (int r = 0; r < 4; r++) {
        int row = w * 4 + r;
        p += hs[row][lane] * w2a + hs[row][lane + 64] * w2b;
    }
#pragma unroll
    for (int off = 32; off; off >>= 1) p += __shfl_xor(p, off);
    if (lane == 0) atomicAdd(&gsum[w >> 1], p);
    __syncthreads();
    if (tid < 2) {
        float rs = gsum[tid] + 8.f * b2_st[0];
        d_out[gblk + tid] = rs * W_out[0] + b_out[0];
    }
}

// ---------------------------------------------------------------------------
// Feature path v8: 256 persistent blocks x 512 thr (8 waves; 155,648 B LDS ->
// 1 block/CU -> 2 waves/SIMD). __launch_bounds__(512) with NO min-occupancy
// arg -> VGPR cap 256 (evidence: 1024-thr blocks pin arch VGPR to 64 and
// spill 700+ MB [r6/r7]; (512,2) capped at 128 and spilled [r4]; (512,2)
// round-3 kernel at 92 VGPR was spill-free). Working set ~160-190 VGPR fits.
// Full weight set staged once; waves free-run over 32-row units (stride 2048).
// Layer-0 kc-outer: per kc load 4x16B h_ft, convert, 16 MFMAs.
// ---------------------------------------------------------------------------
__global__ __launch_bounds__(512) void feature_kernel(
    const float* __restrict__ h_ft, const float* __restrict__ b1_ft,
    const float* __restrict__ W2_ft, const float* __restrict__ b2_ft,
    const float* __restrict__ W_out,
    const unsigned short* __restrict__ wfrag, const float* __restrict__ c_all,
    float* __restrict__ d_out) {
    __shared__ __align__(16) unsigned short lw[77824];   // 155,648 B
    int tid = threadIdx.x;
    {
        const int4* gs = (const int4*)wfrag;
        int4* ls = (int4*)lw;
#pragma unroll
        for (int i = 0; i < 19; i++) ls[i * 512 + tid] = gs[i * 512 + tid];
    }
    __syncthreads();   // only barrier

    const int w = tid >> 6, lane = tid & 63;
    const int c = lane & 15, kg = lane >> 4;
    const int wid = blockIdx.x * 8 + w;
    const short8v* w1l = (const short8v*)lw + lane;

    for (int u = wid; u < 6720; u += 2048) {
        const int rb = u * 32;
        const int row0 = rb + c, row1 = rb + 16 + c;
        const int gA = row0 / NF, gB = row1 / NF;
        const float* a0 = h_ft + (size_t)row0 * NF;
        const float* a1 = h_ft + (size_t)row1 * NF;

        float4v acc0[8], acc1[8];
#pragma unroll
        for (int nc = 0; nc < 8; nc++)
#pragma unroll
            for (int r = 0; r < 4; r++) { acc0[nc][r] = 0.f; acc1[nc][r] = 0.f; }

        // ---- layer 0: kc-outer, load->convert->16 MFMA per kc ----
#pragma unroll
        for (int kc = 0; kc < 7; kc++) {
            const int k0 = kc * 32 + 4 * kg;
            float4u va0 = *(const float4u*)&a0[k0];
            float4u va1 = *(const float4u*)&a1[k0];
            float4u vb0, vb1;
            if (kc < 6) {
                vb0 = *(const float4u*)&a0[k0 + 16];
                vb1 = *(const float4u*)&a1[k0 + 16];
            } else if (kg == 0) {
                float2u t0 = *(const float2u*)&a0[208];
                float2u t1 = *(const float2u*)&a1[208];
                vb0[0] = t0[0]; vb0[1] = t0[1]; vb0[2] = 0.f; vb0[3] = 0.f;
                vb1[0] = t1[0]; vb1[1] = t1[1]; vb1[2] = 0.f; vb1[3] = 0.f;
            } else {
                vb0[0] = vb0[1] = vb0[2] = vb0[3] = 0.f;
                vb1[0] = vb1[1] = vb1[2] = vb1[3] = 0.f;
            }
            short8v bx0, bx1;
#pragma unroll
            for (int r = 0; r < 4; r++) {
                bx0[r]     = f2b(va0[r]);
                bx0[4 + r] = f2b(vb0[r]);
                bx1[r]     = f2b(va1[r]);
                bx1[4 + r] = f2b(vb1[r]);
            }
            __builtin_amdgcn_s_setprio(1);
#pragma unroll
            for (int nc = 0; nc < 8; nc++) {
                short8v wv = w1l[(nc * 7 + kc) * 64];
                acc0[nc] = MFMA16(wv, bx0, acc0[nc]);
                acc1[nc] = MFMA16(wv, bx1, acc1[nc]);
            }
            __builtin_amdgcn_s_setprio(0);
        }

        // ---- transition: +b1, pack next-layer B-frags ----
        short8v bf0[4], bf1[4];
#pragma unroll
        for (int k2 = 0; k2 < 4; k2++) {
            float4a bA = *(const float4a*)&b1_ft[k2 * 32 + 4 * kg];
            float4a bB = *(const float4a*)&b1_ft[k2 * 32 + 16 + 4 * kg];
#pragma unroll
            for (int r = 0; r < 4; r++) {
                bf0[k2][r]     = f2b(acc0[2 * k2][r]     + bA[r]);
                bf0[k2][4 + r] = f2b(acc0[2 * k2 + 1][r] + bB[r]);
                bf1[k2][r]     = f2b(acc1[2 * k2][r]     + bA[r]);
                bf1[k2][4 + r] = f2b(acc1[2 * k2 + 1][r] + bB[r]);
            }
        }

        // ---- conv layers 0,1 ----
#pragma unroll
        for (int l = 0; l < 2; l++) {
            const short8v* wsl = (const short8v*)(lw + 28672 + l * 16384) + lane;
#pragma unroll
            for (int nc = 0; nc < 8; nc++)
#pragma unroll
                for (int r = 0; r < 4; r++) { acc0[nc][r] = 0.f; acc1[nc][r] = 0.f; }
            __builtin_amdgcn_s_setprio(1);
#pragma unroll
            for (int kc = 0; kc < 4; kc++)
#pragma unroll
                for (int nc = 0; nc < 8; nc++) {
                    short8v wv = wsl[(nc * 4 + kc) * 64];
                    acc0[nc] = MFMA16(wv, bf0[kc], acc0[nc]);
                    acc1[nc] = MFMA16(wv, bf1[kc], acc1[nc]);
                }
            __builtin_amdgcn_s_setprio(0);
            const float* cp0 = c_all + (gA * 3 + l) * HID;
            const float* cp1 = c_all + (gB * 3 + l) * HID;
#pragma unroll
            for (int k2 = 0; k2 < 4; k2++) {
                float4a cA0 = *(const float4a*)&cp0[k2 * 32 + 4 * kg];
                float4a cB0 = *(const float4a*)&cp0[k2 * 32 + 16 + 4 * kg];
                float4a cA1 = *(const float4a*)&cp1[k2 * 32 + 4 * kg];
                float4a cB1 = *(const float4a*)&cp1[k2 * 32 + 16 + 4 * kg];
#pragma unroll
                for (int r = 0; r < 4; r++) {
                    bf0[k2][r]     = f2b(fmaxf(acc0[2 * k2][r]     + cA0[r], 0.f));
                    bf0[k2][4 + r] = f2b(fmaxf(acc0[2 * k2 + 1][r] + cB0[r], 0.f));
                    bf1[k2][r]     = f2b(fmaxf(acc1[2 * k2][r]     + cA1[r], 0.f));
                    bf1[k2][4 + r] = f2b(fmaxf(acc1[2 * k2 + 1][r] + cB1[r], 0.f));
                }
            }
        }

        // ---- conv layer 2 + fused epilogue ----
        {
            const short8v* ws2 = (const short8v*)(lw + 61440) + lane;
#pragma unroll
            for (int nc = 0; nc < 8; nc++)
#pragma unroll
                for (int r = 0; r < 4; r++) { acc0[nc][r] = 0.f; acc1[nc][r] = 0.f; }
            __builtin_amdgcn_s_setprio(1);
#pragma unroll
            for (int kc = 0; kc < 4; kc++)
#pragma unroll
                for (int nc = 0; nc < 8; nc++) {
                    short8v wv = ws2[(nc * 4 + kc) * 64];
                    acc0[nc] = MFMA16(wv, bf0[kc], acc0[nc]);
                    acc1[nc] = MFMA16(wv, bf1[kc], acc1[nc]);
                }
            __builtin_amdgcn_s_setprio(0);
            const float* cp0 = c_all + (gA * 3 + 2) * HID;
            const float* cp1 = c_all + (gB * 3 + 2) * HID;
            float p0 = 0.f, p1 = 0.f;
#pragma unroll
            for (int nc = 0; nc < 8; nc++) {
                float4a w2v = *(const float4a*)&W2_ft[nc * 16 + 4 * kg];
                float4a cv0 = *(const float4a*)&cp0[nc * 16 + 4 * kg];
                float4a cv1 = *(const float4a*)&cp1[nc * 16 + 4 * kg];
#pragma unroll
                for (int r = 0; r < 4; r++) {
                    p0 += fmaxf(acc0[nc][r] + cv0[r], 0.f) * w2v[r];
                    p1 += fmaxf(acc1[nc][r] + cv1[r], 0.f) * w2v[r];
                }
            }
            p0 += __shfl_xor(p0, 16); p0 += __shfl_xor(p0, 32);
            p1 += __shfl_xor(p1, 16); p1 += __shfl_xor(p1, 32);
            if (kg == 0) {
                float wo1 = W_out[1], b2v = b2_ft[0];
                atomicAdd(&d_out[gA], (p0 + b2v) * wo1);
                atomicAdd(&d_out[gB], (p1 + b2v) * wo1);
            }
        }
    }
}

extern "C" void kernel_launch(void* const* d_in, const int* in_sizes, int n_in,
                              void* d_out, int out_size, void* d_ws, size_t ws_size,
                              hipStream_t stream) {
    const float* h_st     = (const float*)d_in[0];
    const float* h_ft     = (const float*)d_in[1];
    const float* Wself_tt = (const float*)d_in[2];
    const float* Wneigh_tt= (const float*)d_in[3];
    const float* b_tt     = (const float*)d_in[4];
    const float* Wself_hf = (const float*)d_in[5];
    const float* Wneigh_hf= (const float*)d_in[6];
    const float* b_hf     = (const float*)d_in[7];
    const float* W1_st    = (const float*)d_in[8];
    const float* b1_st    = (const float*)d_in[9];
    const float* W1_ft    = (const float*)d_in[10];
    const float* b1_ft    = (const float*)d_in[11];
    const float* W2_st    = (const float*)d_in[12];
    const float* b2_st    = (const float*)d_in[13];
    const float* W2_ft    = (const float*)d_in[14];
    const float* b2_ft    = (const float*)d_in[15];
    const float* W_out    = (const float*)d_in[16];
    const float* b_out    = (const float*)d_in[17];
    // dense edge lists d_in[18..21] never read

    unsigned short* wfrag = (unsigned short*)d_ws;
    float* c_all = (float*)((char*)d_ws + 155648);

    pre_kernel<<<dim3(816), dim3(256), 0, stream>>>(
        W1_ft, Wself_hf, wfrag,
        h_st, W1_st, b1_st, Wself_tt, Wneigh_tt, b_tt, Wneigh_hf, b_hf,
        W2_st, b2_st, W_out, b_out, c_all, (float*)d_out);
    feature_kernel<<<dim3(256), dim3(512), 0, stream>>>(
        h_ft, b1_ft, W2_ft, b2_ft, W_out, wfrag, c_all, (float*)d_out);
}

// Round 9
// 487.919 us; speedup vs baseline: 1.2609x; 1.2276x over previous
//
#include <hip/hip_runtime.h>
#include <hip/hip_bf16.h>

#define NS 8
#define NF 210
#define HID 128

typedef __attribute__((ext_vector_type(8))) short short8v;     // 8 bf16 = 4 VGPR MFMA A/B frag
typedef __attribute__((ext_vector_type(4))) float float4v;     // MFMA C/D frag
typedef float float4a __attribute__((ext_vector_type(4)));                 // 16B-aligned load
typedef float float4u __attribute__((ext_vector_type(4), aligned(4)));     // 4B-aligned global read
typedef float float2u __attribute__((ext_vector_type(2), aligned(8)));

__device__ __forceinline__ short f2b(float f) {
    __hip_bfloat16 h = __float2bfloat16(f);   // RNE; pairs fuse to v_cvt_pk_bf16_f32
    return __builtin_bit_cast(short, h);
}

#define MFMA16(a, b, cacc) __builtin_amdgcn_mfma_f32_16x16x32_bf16(a, b, cacc, 0, 0, 0)

// ---------------------------------------------------------------------------
// pre_kernel: blocks [0,304) = weight repack; blocks [304,816) = station path.
// Weight repack (W^T A-frags, lane-linear per (nc,kc) -> conflict-free
// ds_read_b128):
//   W1 : [0,28672)         idx = (((nc*7+kc)*4+kg)*16 + c)*8 + j
//   WsL: 28672+l*16384 +   idx = (((nc*4+kc)*4+kg)*16 + c)*8 + j
//   frag elem j of lane (c,kg): n = 16nc+c, k = kc*32+16(j>>2)+4kg+(j&3)
// Station path emits c_all[g][l][:] = mean_l[g] @ Wneigh_hf[l] + b_hf[l] and
// d_out[g] = rs[g]*W_out[0] + b_out (feature kernel atomic-adds rf part).
// ---------------------------------------------------------------------------
__global__ __launch_bounds__(256) void pre_kernel(
    const float* __restrict__ W1_ft, const float* __restrict__ Wself_hf,
    unsigned short* __restrict__ wsb,
    const float* __restrict__ h_st, const float* __restrict__ W1_st, const float* __restrict__ b1_st,
    const float* __restrict__ Wself_tt, const float* __restrict__ Wneigh_tt, const float* __restrict__ b_tt,
    const float* __restrict__ Wneigh_hf, const float* __restrict__ b_hf,
    const float* __restrict__ W2_st, const float* __restrict__ b2_st,
    const float* __restrict__ W_out, const float* __restrict__ b_out,
    float* __restrict__ c_all, float* __restrict__ d_out) {
    __shared__ float hs[16][HID];
    __shared__ float hstile[16][NS];
    __shared__ float m[2][HID];
    __shared__ float ctt[2][HID];
    __shared__ float gsum[2];
    int tid = threadIdx.x;

    if (blockIdx.x < 304) {
        int t = blockIdx.x * 256 + tid;
        if (t < 28672) {
            int j = t & 7, cc = (t >> 3) & 15, kg = (t >> 7) & 3, q = t >> 9;
            int kc = q % 7, nc = q / 7;
            int n = nc * 16 + cc;
            int k = kc * 32 + ((j >> 2) << 4) + (kg << 2) + (j & 3);
            wsb[t] = (unsigned short)f2b(k < NF ? W1_ft[k * HID + n] : 0.f);
        } else {
            int u = t - 28672, l = u >> 14, v = u & 16383;
            int j = v & 7, cc = (v >> 3) & 15, kg = (v >> 7) & 3, kc = (v >> 9) & 3, nc = v >> 11;
            int n = nc * 16 + cc;
            int k = kc * 32 + ((j >> 2) << 4) + (kg << 2) + (j & 3);
            wsb[t] = (unsigned short)f2b(Wself_hf[(l * HID + k) * HID + n]);
        }
        return;
    }

    int bid = blockIdx.x - 304;
    int j = tid & 127, h = tid >> 7;
    int gblk = bid * 2;

    if (tid < 2) gsum[tid] = 0.f;
    if (tid < 128) hstile[tid >> 3][tid & 7] = h_st[bid * 128 + tid];
    __syncthreads();

    {
        float w1r[8];
#pragma unroll
        for (int k = 0; k < 8; k++) w1r[k] = W1_st[k * HID + j];
        float b1 = b1_st[j];
#pragma unroll
        for (int si = 0; si < 8; si++) {
            int s = 2 * si + h;
            float acc = b1;
#pragma unroll
            for (int k = 0; k < 8; k++) acc += hstile[s][k] * w1r[k];
            hs[s][j] = acc;
        }
    }
    __syncthreads();

    for (int l = 0; l < 3; l++) {
        {
            float s0 = 0.f;
#pragma unroll
            for (int s = 0; s < 8; s++) s0 += hs[h * 8 + s][j];
            m[h][j] = s0 * 0.125f;
        }
        __syncthreads();
        {
            float att = b_tt[l * HID + j], ahf = b_hf[l * HID + j];
            const float* wtt = Wneigh_tt + l * HID * HID + j;
            const float* whf = Wneigh_hf + l * HID * HID + j;
            const float* mg = m[h];
#pragma unroll 4
            for (int k = 0; k < HID; k++) {
                float mv = mg[k];
                att += mv * wtt[k * HID];
                ahf += mv * whf[k * HID];
            }
            ctt[h][j] = att;
            c_all[((gblk + h) * 3 + l) * HID + j] = ahf;
        }
        __syncthreads();
        float tmp[8];
#pragma unroll
        for (int si = 0; si < 8; si++) tmp[si] = ctt[(2 * si + h) >> 3][j];
        const float* wsp = Wself_tt + l * HID * HID + j;
        for (int k4 = 0; k4 < HID / 4; k4++) {
            float w0 = wsp[(4 * k4 + 0) * HID];
            float wa = wsp[(4 * k4 + 1) * HID];
            float wb = wsp[(4 * k4 + 2) * HID];
            float wc = wsp[(4 * k4 + 3) * HID];
#pragma unroll
            for (int si = 0; si < 8; si++) {
                float4a hv = *(const float4a*)&hs[2 * si + h][4 * k4];
                tmp[si] += hv.x * w0 + hv.y * wa + hv.z * wb + hv.w * wc;
            }
        }
        __syncthreads();
#pragma unroll
        for (int si = 0; si < 8; si++) hs[2 * si + h][j] = fmaxf(tmp[si], 0.f);
        __syncthreads();
    }

    int w = tid >> 6, lane = tid & 63;
    float w2a = W2_st[lane], w2b = W2_st[lane + 64];
    float p = 0.f;
#pragma unroll
    for (int r = 0; r < 4; r++) {
        int row = w * 4 + r;
        p += hs[row][lane] * w2a + hs[row][lane + 64] * w2b;
    }
#pragma unroll
    for (int off = 32; off; off >>= 1) p += __shfl_xor(p, off);
    if (lane == 0) atomicAdd(&gsum[w >> 1], p);
    __syncthreads();
    if (tid < 2) {
        float rs = gsum[tid] + 8.f * b2_st[0];
        d_out[gblk + tid] = rs * W_out[0] + b_out[0];
    }
}

// ---------------------------------------------------------------------------
// Feature path v9 = v8 + explicit occupancy floor. 155,648 B LDS forces
// 1 block/CU (8 waves = 2 waves/SIMD); amdgpu_waves_per_eu(2,2) tells the
// backend to budget registers for 2 waves/EU -> 256 VGPR/wave (default
// heuristic budgeted for 4 -> cap 128 -> 287 MB spill in r8).
// 256 persistent blocks x 512 thr; full weight set staged once; waves
// free-run over contiguous 32-row unit ranges. Layer-0 kc-outer.
// ---------------------------------------------------------------------------
__global__ __launch_bounds__(512) __attribute__((amdgpu_waves_per_eu(2, 2)))
void feature_kernel(
    const float* __restrict__ h_ft, const float* __restrict__ b1_ft,
    const float* __restrict__ W2_ft, const float* __restrict__ b2_ft,
    const float* __restrict__ W_out,
    const unsigned short* __restrict__ wfrag, const float* __restrict__ c_all,
    float* __restrict__ d_out) {
    __shared__ __align__(16) unsigned short lw[77824];   // 155,648 B
    int tid = threadIdx.x;
    {
        const int4* gs = (const int4*)wfrag;
        int4* ls = (int4*)lw;
#pragma unroll
        for (int i = 0; i < 19; i++) ls[i * 512 + tid] = gs[i * 512 + tid];
    }
    __syncthreads();   // only barrier

    const int w = tid >> 6, lane = tid & 63;
    const int c = lane & 15, kg = lane >> 4;
    const int wid = blockIdx.x * 8 + w;
    const int u0 = (wid * 105) >> 5;          // 6720 units over 2048 waves
    const int u1 = ((wid + 1) * 105) >> 5;
    const short8v* w1l = (const short8v*)lw + lane;

    for (int u = u0; u < u1; ++u) {
        const int rb = u * 32;
        const int row0 = rb + c, row1 = rb + 16 + c;
        const int gA = row0 / NF, gB = row1 / NF;
        const float* a0 = h_ft + (size_t)row0 * NF;
        const float* a1 = h_ft + (size_t)row1 * NF;

        float4v acc0[8], acc1[8];
#pragma unroll
        for (int nc = 0; nc < 8; nc++)
#pragma unroll
            for (int r = 0; r < 4; r++) { acc0[nc][r] = 0.f; acc1[nc][r] = 0.f; }

        // ---- layer 0: kc-outer, load->convert->16 MFMA per kc ----
#pragma unroll
        for (int kc = 0; kc < 7; kc++) {
            const int k0 = kc * 32 + 4 * kg;
            float4u va0 = *(const float4u*)&a0[k0];
            float4u va1 = *(const float4u*)&a1[k0];
            float4u vb0, vb1;
            if (kc < 6) {
                vb0 = *(const float4u*)&a0[k0 + 16];
                vb1 = *(const float4u*)&a1[k0 + 16];
            } else if (kg == 0) {
                float2u t0 = *(const float2u*)&a0[208];
                float2u t1 = *(const float2u*)&a1[208];
                vb0[0] = t0[0]; vb0[1] = t0[1]; vb0[2] = 0.f; vb0[3] = 0.f;
                vb1[0] = t1[0]; vb1[1] = t1[1]; vb1[2] = 0.f; vb1[3] = 0.f;
            } else {
                vb0[0] = vb0[1] = vb0[2] = vb0[3] = 0.f;
                vb1[0] = vb1[1] = vb1[2] = vb1[3] = 0.f;
            }
            short8v bx0, bx1;
#pragma unroll
            for (int r = 0; r < 4; r++) {
                bx0[r]     = f2b(va0[r]);
                bx0[4 + r] = f2b(vb0[r]);
                bx1[r]     = f2b(va1[r]);
                bx1[4 + r] = f2b(vb1[r]);
            }
            __builtin_amdgcn_s_setprio(1);
#pragma unroll
            for (int nc = 0; nc < 8; nc++) {
                short8v wv = w1l[(nc * 7 + kc) * 64];
                acc0[nc] = MFMA16(wv, bx0, acc0[nc]);
                acc1[nc] = MFMA16(wv, bx1, acc1[nc]);
            }
            __builtin_amdgcn_s_setprio(0);
        }

        // ---- transition: +b1, pack next-layer B-frags ----
        short8v bf0[4], bf1[4];
#pragma unroll
        for (int k2 = 0; k2 < 4; k2++) {
            float4a bA = *(const float4a*)&b1_ft[k2 * 32 + 4 * kg];
            float4a bB = *(const float4a*)&b1_ft[k2 * 32 + 16 + 4 * kg];
#pragma unroll
            for (int r = 0; r < 4; r++) {
                bf0[k2][r]     = f2b(acc0[2 * k2][r]     + bA[r]);
                bf0[k2][4 + r] = f2b(acc0[2 * k2 + 1][r] + bB[r]);
                bf1[k2][r]     = f2b(acc1[2 * k2][r]     + bA[r]);
                bf1[k2][4 + r] = f2b(acc1[2 * k2 + 1][r] + bB[r]);
            }
        }

        // ---- conv layers 0,1 ----
#pragma unroll
        for (int l = 0; l < 2; l++) {
            const short8v* wsl = (const short8v*)(lw + 28672 + l * 16384) + lane;
#pragma unroll
            for (int nc = 0; nc < 8; nc++)
#pragma unroll
                for (int r = 0; r < 4; r++) { acc0[nc][r] = 0.f; acc1[nc][r] = 0.f; }
            __builtin_amdgcn_s_setprio(1);
#pragma unroll
            for (int kc = 0; kc < 4; kc++)
#pragma unroll
                for (int nc = 0; nc < 8; nc++) {
                    short8v wv = wsl[(nc * 4 + kc) * 64];
                    acc0[nc] = MFMA16(wv, bf0[kc], acc0[nc]);
                    acc1[nc] = MFMA16(wv, bf1[kc], acc1[nc]);
                }
            __builtin_amdgcn_s_setprio(0);
            const float* cp0 = c_all + (gA * 3 + l) * HID;
            const float* cp1 = c_all + (gB * 3 + l) * HID;
#pragma unroll
            for (int k2 = 0; k2 < 4; k2++) {
                float4a cA0 = *(const float4a*)&cp0[k2 * 32 + 4 * kg];
                float4a cB0 = *(const float4a*)&cp0[k2 * 32 + 16 + 4 * kg];
                float4a cA1 = *(const float4a*)&cp1[k2 * 32 + 4 * kg];
                float4a cB1 = *(const float4a*)&cp1[k2 * 32 + 16 + 4 * kg];
#pragma unroll
                for (int r = 0; r < 4; r++) {
                    bf0[k2][r]     = f2b(fmaxf(acc0[2 * k2][r]     + cA0[r], 0.f));
                    bf0[k2][4 + r] = f2b(fmaxf(acc0[2 * k2 + 1][r] + cB0[r], 0.f));
                    bf1[k2][r]     = f2b(fmaxf(acc1[2 * k2][r]     + cA1[r], 0.f));
                    bf1[k2][4 + r] = f2b(fmaxf(acc1[2 * k2 + 1][r] + cB1[r], 0.f));
                }
            }
        }

        // ---- conv layer 2 + fused epilogue ----
        {
            const short8v* ws2 = (const short8v*)(lw + 61440) + lane;
#pragma unroll
            for (int nc = 0; nc < 8; nc++)
#pragma unroll
                for (int r = 0; r < 4; r++) { acc0[nc][r] = 0.f; acc1[nc][r] = 0.f; }
            __builtin_amdgcn_s_setprio(1);
#pragma unroll
            for (int kc = 0; kc < 4; kc++)
#pragma unroll
                for (int nc = 0; nc < 8; nc++) {
                    short8v wv = ws2[(nc * 4 + kc) * 64];
                    acc0[nc] = MFMA16(wv, bf0[kc], acc0[nc]);
                    acc1[nc] = MFMA16(wv, bf1[kc], acc1[nc]);
                }
            __builtin_amdgcn_s_setprio(0);
            const float* cp0 = c_all + (gA * 3 + 2) * HID;
            const float* cp1 = c_all + (gB * 3 + 2) * HID;
            float p0 = 0.f, p1 = 0.f;
#pragma unroll
            for (int nc = 0; nc < 8; nc++) {
                float4a w2v = *(const float4a*)&W2_ft[nc * 16 + 4 * kg];
                float4a cv0 = *(const float4a*)&cp0[nc * 16 + 4 * kg];
                float4a cv1 = *(const float4a*)&cp1[nc * 16 + 4 * kg];
#pragma unroll
                for (int r = 0; r < 4; r++) {
                    p0 += fmaxf(acc0[nc][r] + cv0[r], 0.f) * w2v[r];
                    p1 += fmaxf(acc1[nc][r] + cv1[r], 0.f) * w2v[r];
                }
            }
            p0 += __shfl_xor(p0, 16); p0 += __shfl_xor(p0, 32);
            p1 += __shfl_xor(p1, 16); p1 += __shfl_xor(p1, 32);
            if (kg == 0) {
                float wo1 = W_out[1], b2v = b2_ft[0];
                atomicAdd(&d_out[gA], (p0 + b2v) * wo1);
                atomicAdd(&d_out[gB], (p1 + b2v) * wo1);
            }
        }
    }
}

extern "C" void kernel_launch(void* const* d_in, const int* in_sizes, int n_in,
                              void* d_out, int out_size, void* d_ws, size_t ws_size,
                              hipStream_t stream) {
    const float* h_st     = (const float*)d_in[0];
    const float* h_ft     = (const float*)d_in[1];
    const float* Wself_tt = (const float*)d_in[2];
    const float* Wneigh_tt= (const float*)d_in[3];
    const float* b_tt     = (const float*)d_in[4];
    const float* Wself_hf = (const float*)d_in[5];
    const float* Wneigh_hf= (const float*)d_in[6];
    const float* b_hf     = (const float*)d_in[7];
    const float* W1_st    = (const float*)d_in[8];
    const float* b1_st    = (const float*)d_in[9];
    const float* W1_ft    = (const float*)d_in[10];
    const float* b1_ft    = (const float*)d_in[11];
    const float* W2_st    = (const float*)d_in[12];
    const float* b2_st    = (const float*)d_in[13];
    const float* W2_ft    = (const float*)d_in[14];
    const float* b2_ft    = (const float*)d_in[15];
    const float* W_out    = (const float*)d_in[16];
    const float* b_out    = (const float*)d_in[17];
    // dense edge lists d_in[18..21] never read

    unsigned short* wfrag = (unsigned short*)d_ws;
    float* c_all = (float*)((char*)d_ws + 155648);

    pre_kernel<<<dim3(816), dim3(256), 0, stream>>>(
        W1_ft, Wself_hf, wfrag,
        h_st, W1_st, b1_st, Wself_tt, Wneigh_tt, b_tt, Wneigh_hf, b_hf,
        W2_st, b2_st, W_out, b_out, c_all, (float*)d_out);
    feature_kernel<<<dim3(256), dim3(512), 0, stream>>>(
        h_ft, b1_ft, W2_ft, b2_ft, W_out, wfrag, c_all, (float*)d_out);
}